// Round 15
// baseline (63.265 us; speedup 1.0000x reference)
//
#include <hip/hip_runtime.h>

#define BB   32
#define HH   512
#define WW   512
#define SH   364
#define SW   280
#define RAD  15
#define NK   96
#define OMN  (HH*WW)          // 262144
#define PF4  (OMN/4)          // 65536 f4 per (b,c) plane

#define OH   16               // output tile rows per block
#define OW   32               // output tile cols per block
#define NRM  13               // max w3 rows a tile needs
#define NCM  19               // max w3 cols a tile needs (valid cols 0..18)
#define WRM  (NRM + 2*RAD)    // 43 w2 rows
#define HRM  (NRM + 4*RAD)    // 73 hm rows
// padded col widths (16B-multiple rows for f4 LDS loads)
#define HCP  84               // hm cols: h1 window reads up to (12+8)*4+3 = 83 < 84
#define WCP  52               // w2/t1 cols: 49 valid, groups cover 0..51
#define NCP  20               // t2/w3 cols: valid 0..18, col 19 garbage (never read)
#define G1   13               // x4-groups over w2/t1 cols (13*4 = 52)
#define G2   5                // x4-groups over t2/w3 cols (5*4 = 20)

typedef float f4 __attribute__((ext_vector_type(4)));

// derived keypoint j (0..95) of batch b -> rounded clipped (ix, iy) in heatmap space
__device__ __forceinline__ void point_ij(const float* __restrict__ lm, int b, int j,
                                         int& ix, int& iy) {
    int idx; float s;
    if      (j <  6) { idx = 30 + j;        s = 1.0f; }   // p0
    else if (j < 12) { idx = 30 + (j - 6);  s = 1.5f; }   // p01
    else if (j < 25) { idx =  2 + (j - 12); s = 0.7f; }   // p12
    else if (j < 38) { idx =  2 + (j - 25); s = 0.9f; }   // p13
    else if (j < 51) { idx =  2 + (j - 38); s = 0.5f; }   // p11
    else if (j < 71) { idx = 48 + (j - 51); s = 1.0f; }   // p2
    else if (j < 76) { idx =  6 + (j - 71); s = 1.0f; }   // p3
    else             { idx = 48 + (j - 76); s = 1.3f; }   // p21
    const float scal = 364.0f / 512.0f;   // exact 0.7109375
    float lx = lm[b * 136 + idx * 2 + 0] * scal;
    float ly = lm[b * 136 + idx * 2 + 1] * scal;
    float kx, ky;
    if (s == 1.0f) { kx = lx; ky = ly; }
    else {
        float cx = lm[b * 136 + 30 * 2 + 0] * scal;
        float cy = lm[b * 136 + 30 * 2 + 1] * scal;
        kx = (lx - cx) * s + cx;
        ky = (ly - cy) * s + cy;
    }
    ix = __float2int_rn(fminf(fmaxf(kx, 0.0f), (float)(SW - 1)));
    iy = __float2int_rn(fminf(fmaxf(ky, 0.0f), (float)(SH - 1)));
}

// ---- k_fused (R13 structure + w2S-overlay + 3 blocks/CU) ----
// 512 blocks of 16x32 output tiles; mask tile in LDS then stream 48 planes
// per thread-group. LDS ~46.4 KB -> 3 blocks/CU, 12 waves/CU.
__global__ __launch_bounds__(256, 3) void k_fused(const float* __restrict__ lm,
                                                  const float* __restrict__ wt,
                                                  const f4* __restrict__ face,
                                                  f4* __restrict__ out) {
    __shared__ float gwl[31];
    __shared__ alignas(16) float hmS[HRM][HCP];   // 73x84; reused as w2S[43][52]
    __shared__ alignas(16) float t1 [HRM][WCP];   // 73x52 after blur1 h-pass
    __shared__ alignas(16) float t2 [WRM][NCP];   // 43x20 after blur2 h-pass
    __shared__ alignas(16) float w3S[NRM][NCP];   // 13x20 final blurred region
    __shared__ alignas(16) float maskS[OH][OW];   // 16x32 (1-mask) tile
    float (*w2S)[WCP] = (float(*)[WCP])hmS;       // overlay: hmS dead after h1

    const int tid = threadIdx.x;
    const int h0 = blockIdx.y * OH, w0 = blockIdx.x * OW;
    const float sy = (float)SH / (float)HH;   // 0.7109375
    const float sx = (float)SW / (float)WW;   // 0.546875

    // streaming-phase coordinates (needed early for prefetch addresses)
    const int j   = tid & 127;
    const int grp = tid >> 7;                  // 0 or 1
    const int dh  = j >> 3, dw4 = (j & 7) << 2;
    const long off = (long)(h0 + dh) * (WW / 4) + ((w0 + dw4) >> 2);

    // exact normalized 1D profile: gn[j] = W[15][j]/sqrt(W[15][15]) => gn_i*gn_j == W[i][j]
    if (tid < 31) gwl[tid] = wt[15 * 31 + tid] / sqrtf(wt[15 * 31 + 15]);

    // w3 rows/cols this tile needs (monotone coord map, clamped)
    const int hl = h0 + OH - 1, wl = w0 + OW - 1;
    float fy0 = fmaxf(((float)h0 + 0.5f) * sy - 0.5f, 0.0f);
    float fyl = fminf(((float)hl + 0.5f) * sy - 0.5f, (float)(SH - 1));
    int rbase = (int)fy0;
    int rend  = min(SH - 1, (int)fyl + 1);
    float fx0 = fmaxf(((float)w0 + 0.5f) * sx - 0.5f, 0.0f);
    float fxl = fminf(((float)wl + 0.5f) * sx - 0.5f, (float)(SW - 1));
    int cbase = (int)fx0;
    int cend  = min(SW - 1, (int)fxl + 1);
    int NR = rend - rbase + 1;          // <= 13
    int NC = cend - cbase + 1;          // <= 19
    int HR = NR + 4 * RAD, HC = NC + 4 * RAD;   // hm region consumed (<= 73 x 79)

    // zero heatmap region (full padded width -> no garbage anywhere in hmS)
    for (int i = tid; i < HRM * HCP; i += 256) ((float*)hmS)[i] = 0.0f;
    __syncthreads();

    float g[31];
    #pragma unroll
    for (int k = 0; k < 31; ++k) g[k] = gwl[k];

    // scatter all 3072 derived points landing in this block's hm region
    for (int p = tid; p < BB * NK; p += 256) {
        int b = p / NK, jj = p - b * NK;
        int ix, iy;
        point_ij(lm, b, jj, ix, iy);
        int ly = iy - (rbase - 2 * RAD), lx = ix - (cbase - 2 * RAD);
        if (ly >= 0 && ly < HR && lx >= 0 && lx < HC) hmS[ly][lx] = 1.0f;
    }

    // ---- prefetch 16 of this thread's 48 planes (33 MB across the grid);
    // conv phases issue zero global ops, so these ride under the mask compute.
    f4 pf0  = face[(long)(grp +  0) * PF4 + off];
    f4 pf1  = face[(long)(grp +  2) * PF4 + off];
    f4 pf2  = face[(long)(grp +  4) * PF4 + off];
    f4 pf3  = face[(long)(grp +  6) * PF4 + off];
    f4 pf4  = face[(long)(grp +  8) * PF4 + off];
    f4 pf5  = face[(long)(grp + 10) * PF4 + off];
    f4 pf6  = face[(long)(grp + 12) * PF4 + off];
    f4 pf7  = face[(long)(grp + 14) * PF4 + off];
    f4 pf8  = face[(long)(grp + 16) * PF4 + off];
    f4 pf9  = face[(long)(grp + 18) * PF4 + off];
    f4 pf10 = face[(long)(grp + 20) * PF4 + off];
    f4 pf11 = face[(long)(grp + 22) * PF4 + off];
    f4 pf12 = face[(long)(grp + 24) * PF4 + off];
    f4 pf13 = face[(long)(grp + 26) * PF4 + off];
    f4 pf14 = face[(long)(grp + 28) * PF4 + off];
    f4 pf15 = face[(long)(grp + 30) * PF4 + off];

    __syncthreads();

    // blur1 horizontal: 4 outputs/thread; window loaded as 9 f4 (b128) reads.
    for (int it = tid; it < HRM * G1; it += 256) {
        int y = it / G1, c0g = it - y * G1;
        f4 rb[9];
        #pragma unroll
        for (int k = 0; k < 9; ++k) rb[k] = *(const f4*)&hmS[y][(c0g + k) * 4];
        float r[36];
        #pragma unroll
        for (int k = 0; k < 9; ++k) {
            r[4*k+0] = rb[k][0]; r[4*k+1] = rb[k][1];
            r[4*k+2] = rb[k][2]; r[4*k+3] = rb[k][3];
        }
        f4 o;
        #pragma unroll
        for (int q = 0; q < 4; ++q) {
            float acc = 0.0f;
            #pragma unroll
            for (int d = 0; d < 31; ++d) acc += g[d] * r[q + d];
            o[q] = acc;
        }
        *(f4*)&t1[y][c0g * 4] = o;
    }
    __syncthreads();   // hmS fully consumed; safe to overwrite as w2S

    // blur1 vertical + threshold + image-bounds zeroing: 31 f4 loads, 1 f4 store.
    for (int it = tid; it < WRM * G1; it += 256) {
        int y = it / G1, c0 = (it - y * G1) * 4;
        f4 acc = {0.0f, 0.0f, 0.0f, 0.0f};
        #pragma unroll
        for (int d = 0; d < 31; ++d) {
            f4 v = *(const f4*)&t1[y + d][c0];
            acc += v * g[d];
        }
        int gy = rbase - RAD + y;
        bool rowok = (gy >= 0 && gy < SH);
        f4 o;
        #pragma unroll
        for (int q = 0; q < 4; ++q) {
            float v = acc[q];
            v = (v > 1e-7f) ? 1.0f : v;
            int gx = cbase - RAD + c0 + q;
            o[q] = (rowok && gx >= 0 && gx < SW) ? v : 0.0f;
        }
        *(f4*)&w2S[y][c0] = o;
    }
    __syncthreads();

    // blur2 horizontal: f4-window method (reads w2S cols <= 16+35 = 51 < 52).
    for (int it = tid; it < WRM * G2; it += 256) {
        int y = it / G2, c0g = it - y * G2;
        f4 rb[9];
        #pragma unroll
        for (int k = 0; k < 9; ++k) rb[k] = *(const f4*)&w2S[y][(c0g + k) * 4];
        float r[36];
        #pragma unroll
        for (int k = 0; k < 9; ++k) {
            r[4*k+0] = rb[k][0]; r[4*k+1] = rb[k][1];
            r[4*k+2] = rb[k][2]; r[4*k+3] = rb[k][3];
        }
        f4 o;
        #pragma unroll
        for (int q = 0; q < 4; ++q) {
            float acc = 0.0f;
            #pragma unroll
            for (int d = 0; d < 31; ++d) acc += g[d] * r[q + d];
            o[q] = acc;
        }
        *(f4*)&t2[y][c0g * 4] = o;
    }
    __syncthreads();

    // blur2 vertical: f4 loads.
    for (int it = tid; it < NRM * G2; it += 256) {
        int y = it / G2, c0 = (it - y * G2) * 4;
        f4 acc = {0.0f, 0.0f, 0.0f, 0.0f};
        #pragma unroll
        for (int d = 0; d < 31; ++d) {
            f4 v = *(const f4*)&t2[y + d][c0];
            acc += v * g[d];
        }
        *(f4*)&w3S[y][c0] = acc;
    }
    __syncthreads();

    // bilinear resize + (1 - v) -> maskS (LDS)
    for (int i = tid; i < OH * OW; i += 256) {
        int ddh = i / OW, ddw = i - ddh * OW;
        int h = h0 + ddh, w = w0 + ddw;
        float fy = fminf(fmaxf(((float)h + 0.5f) * sy - 0.5f, 0.0f), (float)(SH - 1));
        float fx = fminf(fmaxf(((float)w + 0.5f) * sx - 0.5f, 0.0f), (float)(SW - 1));
        int y0 = (int)fy, x0 = (int)fx;
        int y1 = min(y0 + 1, SH - 1), x1 = min(x0 + 1, SW - 1);
        float ty = fy - (float)y0, tx = fx - (float)x0;
        int ly0 = y0 - rbase, ly1 = y1 - rbase;
        int lx0 = x0 - cbase, lx1 = x1 - cbase;
        float v00 = w3S[ly0][lx0], v01 = w3S[ly0][lx1];
        float v10 = w3S[ly1][lx0], v11 = w3S[ly1][lx1];
        float v = (1.0f - ty) * ((1.0f - tx) * v00 + tx * v01)
                +         ty  * ((1.0f - tx) * v10 + tx * v11);
        maskS[ddh][ddw] = 1.0f - v;
    }
    __syncthreads();

    // ---- streaming phase ----
    const f4 m = *(const f4*)&maskS[dh][dw4];
    __builtin_nontemporal_store(pf0  * m, &out[(long)(grp +  0) * PF4 + off]);
    __builtin_nontemporal_store(pf1  * m, &out[(long)(grp +  2) * PF4 + off]);
    __builtin_nontemporal_store(pf2  * m, &out[(long)(grp +  4) * PF4 + off]);
    __builtin_nontemporal_store(pf3  * m, &out[(long)(grp +  6) * PF4 + off]);
    __builtin_nontemporal_store(pf4  * m, &out[(long)(grp +  8) * PF4 + off]);
    __builtin_nontemporal_store(pf5  * m, &out[(long)(grp + 10) * PF4 + off]);
    __builtin_nontemporal_store(pf6  * m, &out[(long)(grp + 12) * PF4 + off]);
    __builtin_nontemporal_store(pf7  * m, &out[(long)(grp + 14) * PF4 + off]);
    __builtin_nontemporal_store(pf8  * m, &out[(long)(grp + 16) * PF4 + off]);
    __builtin_nontemporal_store(pf9  * m, &out[(long)(grp + 18) * PF4 + off]);
    __builtin_nontemporal_store(pf10 * m, &out[(long)(grp + 20) * PF4 + off]);
    __builtin_nontemporal_store(pf11 * m, &out[(long)(grp + 22) * PF4 + off]);
    __builtin_nontemporal_store(pf12 * m, &out[(long)(grp + 24) * PF4 + off]);
    __builtin_nontemporal_store(pf13 * m, &out[(long)(grp + 26) * PF4 + off]);
    __builtin_nontemporal_store(pf14 * m, &out[(long)(grp + 28) * PF4 + off]);
    __builtin_nontemporal_store(pf15 * m, &out[(long)(grp + 30) * PF4 + off]);
    // remaining 32 planes
    #pragma unroll 8
    for (int k = 16; k < 48; ++k) {
        long idx = (long)(grp + 2 * k) * PF4 + off;
        f4 a = face[idx];
        __builtin_nontemporal_store(a * m, &out[idx]);
    }
}

extern "C" void kernel_launch(void* const* d_in, const int* in_sizes, int n_in,
                              void* d_out, int out_size, void* d_ws, size_t ws_size,
                              hipStream_t stream) {
    const float* face = (const float*)d_in[0];   // (32,3,512,512)
    const float* lm   = (const float*)d_in[1];   // (32,68,2)
    const float* wt   = (const float*)d_in[2];   // (1,1,31,31) gaussian, normalized

    // single fused kernel: 16x32 grid of 32x16 output tiles = 512 blocks (3/CU)
    k_fused<<<dim3(WW / OW, HH / OH), 256, 0, stream>>>(
        lm, wt, (const f4*)face, (f4*)d_out);
}

// Round 16
// 50.823 us; speedup vs baseline: 1.2448x; 1.2448x over previous
//
#include <hip/hip_runtime.h>

#define BB   32
#define HH   512
#define WW   512
#define SH   364
#define SW   280
#define RAD  15
#define NK   96
#define OMN  (HH*WW)          // 262144
#define PF4  (OMN/4)          // 65536 f4 per (b,c) plane

#define OH   16               // output tile rows per block
#define OW   32               // output tile cols per block
#define NRM  13               // max w3 rows a tile needs
#define NCM  19               // max w3 cols a tile needs (valid cols 0..18)
#define WRM  (NRM + 2*RAD)    // 43 w2 rows
#define HRM  (NRM + 4*RAD)    // 73 hm rows
// padded col widths (16B-multiple rows for f4 LDS loads)
#define HCP  84               // hm cols: h1 window needs c0*4+36 <= 84 (c0g<=12) exact
#define WCP  52               // w2/t1 cols: h2 window needs 16+36 <= 52 exact
#define NCP  20               // t2/w3 cols: valid 0..18, col 19 garbage (never read)
#define G1   13               // x4-groups over w2/t1 cols (13*4 = 52)
#define G2   5                // x4-groups over t2/w3 cols (5*4 = 20)

typedef float f4 __attribute__((ext_vector_type(4)));

// derived keypoint j (0..95) of batch b -> rounded clipped (ix, iy) in heatmap space
__device__ __forceinline__ void point_ij(const float* __restrict__ lm, int b, int j,
                                         int& ix, int& iy) {
    int idx; float s;
    if      (j <  6) { idx = 30 + j;        s = 1.0f; }   // p0
    else if (j < 12) { idx = 30 + (j - 6);  s = 1.5f; }   // p01
    else if (j < 25) { idx =  2 + (j - 12); s = 0.7f; }   // p12
    else if (j < 38) { idx =  2 + (j - 25); s = 0.9f; }   // p13
    else if (j < 51) { idx =  2 + (j - 38); s = 0.5f; }   // p11
    else if (j < 71) { idx = 48 + (j - 51); s = 1.0f; }   // p2
    else if (j < 76) { idx =  6 + (j - 71); s = 1.0f; }   // p3
    else             { idx = 48 + (j - 76); s = 1.3f; }   // p21
    const float scal = 364.0f / 512.0f;   // exact 0.7109375
    float lx = lm[b * 136 + idx * 2 + 0] * scal;
    float ly = lm[b * 136 + idx * 2 + 1] * scal;
    float kx, ky;
    if (s == 1.0f) { kx = lx; ky = ly; }
    else {
        float cx = lm[b * 136 + 30 * 2 + 0] * scal;
        float cy = lm[b * 136 + 30 * 2 + 1] * scal;
        kx = (lx - cx) * s + cx;
        ky = (ly - cy) * s + cy;
    }
    ix = __float2int_rn(fminf(fmaxf(kx, 0.0f), (float)(SW - 1)));
    iy = __float2int_rn(fminf(fmaxf(ky, 0.0f), (float)(SH - 1)));
}

// ---- k_fused (R13 exact): mask tile in LDS, then stream 48 planes/group ----
// 512 blocks of 16x32 tiles; 55.8 KB LDS pins occupancy at 2 blocks/CU —
// measured optimum (1/CU starves streaming [R14]; 3/CU thrashes L3 and
// inflates HBM write traffic [R15]).
__global__ __launch_bounds__(256, 2) void k_fused(const float* __restrict__ lm,
                                                  const float* __restrict__ wt,
                                                  const f4* __restrict__ face,
                                                  f4* __restrict__ out) {
    __shared__ float gwl[31];
    __shared__ alignas(16) float hmS[HRM][HCP];   // 73x84 binary heatmap region
    __shared__ alignas(16) float t1 [HRM][WCP];   // 73x52 after blur1 h-pass
    __shared__ alignas(16) float w2S[WRM][WCP];   // 43x52 thresholded blur1
    __shared__ alignas(16) float t2 [WRM][NCP];   // 43x20 after blur2 h-pass
    __shared__ alignas(16) float w3S[NRM][NCP];   // 13x20 final blurred region
    __shared__ alignas(16) float maskS[OH][OW];   // 16x32 (1-mask) tile

    const int tid = threadIdx.x;
    const int h0 = blockIdx.y * OH, w0 = blockIdx.x * OW;
    const float sy = (float)SH / (float)HH;   // 0.7109375
    const float sx = (float)SW / (float)WW;   // 0.546875

    // streaming-phase coordinates (needed early for prefetch addresses)
    const int j   = tid & 127;
    const int grp = tid >> 7;                  // 0 or 1
    const int dh  = j >> 3, dw4 = (j & 7) << 2;
    const long off = (long)(h0 + dh) * (WW / 4) + ((w0 + dw4) >> 2);

    // exact normalized 1D profile: gn[j] = W[15][j]/sqrt(W[15][15]) => gn_i*gn_j == W[i][j]
    if (tid < 31) gwl[tid] = wt[15 * 31 + tid] / sqrtf(wt[15 * 31 + 15]);

    // w3 rows/cols this tile needs (monotone coord map, clamped)
    const int hl = h0 + OH - 1, wl = w0 + OW - 1;
    float fy0 = fmaxf(((float)h0 + 0.5f) * sy - 0.5f, 0.0f);
    float fyl = fminf(((float)hl + 0.5f) * sy - 0.5f, (float)(SH - 1));
    int rbase = (int)fy0;
    int rend  = min(SH - 1, (int)fyl + 1);
    float fx0 = fmaxf(((float)w0 + 0.5f) * sx - 0.5f, 0.0f);
    float fxl = fminf(((float)wl + 0.5f) * sx - 0.5f, (float)(SW - 1));
    int cbase = (int)fx0;
    int cend  = min(SW - 1, (int)fxl + 1);
    int NR = rend - rbase + 1;          // <= 13
    int NC = cend - cbase + 1;          // <= 19
    int HR = NR + 4 * RAD, HC = NC + 4 * RAD;   // hm region consumed (<= 73 x 79)

    // zero heatmap region (full padded width -> no garbage anywhere in hmS)
    for (int i = tid; i < HRM * HCP; i += 256) ((float*)hmS)[i] = 0.0f;
    __syncthreads();

    float g[31];
    #pragma unroll
    for (int k = 0; k < 31; ++k) g[k] = gwl[k];

    // scatter all 3072 derived points landing in this block's hm region
    for (int p = tid; p < BB * NK; p += 256) {
        int b = p / NK, jj = p - b * NK;
        int ix, iy;
        point_ij(lm, b, jj, ix, iy);
        int ly = iy - (rbase - 2 * RAD), lx = ix - (cbase - 2 * RAD);
        if (ly >= 0 && ly < HR && lx >= 0 && lx < HC) hmS[ly][lx] = 1.0f;
    }

    // ---- prefetch 16 of this thread's 48 planes (33 MB across the grid).
    // Conv phases below issue ZERO global ops -> no vmcnt waits -> these
    // HBM reads complete entirely under the mask compute. 64 VGPRs.
    f4 pf0  = face[(long)(grp +  0) * PF4 + off];
    f4 pf1  = face[(long)(grp +  2) * PF4 + off];
    f4 pf2  = face[(long)(grp +  4) * PF4 + off];
    f4 pf3  = face[(long)(grp +  6) * PF4 + off];
    f4 pf4  = face[(long)(grp +  8) * PF4 + off];
    f4 pf5  = face[(long)(grp + 10) * PF4 + off];
    f4 pf6  = face[(long)(grp + 12) * PF4 + off];
    f4 pf7  = face[(long)(grp + 14) * PF4 + off];
    f4 pf8  = face[(long)(grp + 16) * PF4 + off];
    f4 pf9  = face[(long)(grp + 18) * PF4 + off];
    f4 pf10 = face[(long)(grp + 20) * PF4 + off];
    f4 pf11 = face[(long)(grp + 22) * PF4 + off];
    f4 pf12 = face[(long)(grp + 24) * PF4 + off];
    f4 pf13 = face[(long)(grp + 26) * PF4 + off];
    f4 pf14 = face[(long)(grp + 28) * PF4 + off];
    f4 pf15 = face[(long)(grp + 30) * PF4 + off];

    __syncthreads();

    // blur1 horizontal: 4 outputs/thread; window loaded as 9 f4 (b128) reads.
    for (int it = tid; it < HRM * G1; it += 256) {
        int y = it / G1, c0g = it - y * G1;
        f4 rb[9];
        #pragma unroll
        for (int k = 0; k < 9; ++k) rb[k] = *(const f4*)&hmS[y][(c0g + k) * 4];
        float r[36];
        #pragma unroll
        for (int k = 0; k < 9; ++k) {
            r[4*k+0] = rb[k][0]; r[4*k+1] = rb[k][1];
            r[4*k+2] = rb[k][2]; r[4*k+3] = rb[k][3];
        }
        f4 o;
        #pragma unroll
        for (int q = 0; q < 4; ++q) {
            float acc = 0.0f;
            #pragma unroll
            for (int d = 0; d < 31; ++d) acc += g[d] * r[q + d];
            o[q] = acc;
        }
        *(f4*)&t1[y][c0g * 4] = o;
    }
    __syncthreads();

    // blur1 vertical + threshold + image-bounds zeroing: 31 f4 loads, 1 f4 store.
    for (int it = tid; it < WRM * G1; it += 256) {
        int y = it / G1, c0 = (it - y * G1) * 4;
        f4 acc = {0.0f, 0.0f, 0.0f, 0.0f};
        #pragma unroll
        for (int d = 0; d < 31; ++d) {
            f4 v = *(const f4*)&t1[y + d][c0];
            acc += v * g[d];
        }
        int gy = rbase - RAD + y;
        bool rowok = (gy >= 0 && gy < SH);
        f4 o;
        #pragma unroll
        for (int q = 0; q < 4; ++q) {
            float v = acc[q];
            v = (v > 1e-7f) ? 1.0f : v;
            int gx = cbase - RAD + c0 + q;
            o[q] = (rowok && gx >= 0 && gx < SW) ? v : 0.0f;
        }
        *(f4*)&w2S[y][c0] = o;
    }
    __syncthreads();

    // blur2 horizontal: f4-window method (reads w2S cols <= 16+35 = 51 < 52).
    for (int it = tid; it < WRM * G2; it += 256) {
        int y = it / G2, c0g = it - y * G2;
        f4 rb[9];
        #pragma unroll
        for (int k = 0; k < 9; ++k) rb[k] = *(const f4*)&w2S[y][(c0g + k) * 4];
        float r[36];
        #pragma unroll
        for (int k = 0; k < 9; ++k) {
            r[4*k+0] = rb[k][0]; r[4*k+1] = rb[k][1];
            r[4*k+2] = rb[k][2]; r[4*k+3] = rb[k][3];
        }
        f4 o;
        #pragma unroll
        for (int q = 0; q < 4; ++q) {
            float acc = 0.0f;
            #pragma unroll
            for (int d = 0; d < 31; ++d) acc += g[d] * r[q + d];
            o[q] = acc;
        }
        *(f4*)&t2[y][c0g * 4] = o;
    }
    __syncthreads();

    // blur2 vertical: f4 loads.
    for (int it = tid; it < NRM * G2; it += 256) {
        int y = it / G2, c0 = (it - y * G2) * 4;
        f4 acc = {0.0f, 0.0f, 0.0f, 0.0f};
        #pragma unroll
        for (int d = 0; d < 31; ++d) {
            f4 v = *(const f4*)&t2[y + d][c0];
            acc += v * g[d];
        }
        *(f4*)&w3S[y][c0] = acc;
    }
    __syncthreads();

    // bilinear resize + (1 - v) -> maskS (LDS)
    for (int i = tid; i < OH * OW; i += 256) {
        int ddh = i / OW, ddw = i - ddh * OW;
        int h = h0 + ddh, w = w0 + ddw;
        float fy = fminf(fmaxf(((float)h + 0.5f) * sy - 0.5f, 0.0f), (float)(SH - 1));
        float fx = fminf(fmaxf(((float)w + 0.5f) * sx - 0.5f, 0.0f), (float)(SW - 1));
        int y0 = (int)fy, x0 = (int)fx;
        int y1 = min(y0 + 1, SH - 1), x1 = min(x0 + 1, SW - 1);
        float ty = fy - (float)y0, tx = fx - (float)x0;
        int ly0 = y0 - rbase, ly1 = y1 - rbase;
        int lx0 = x0 - cbase, lx1 = x1 - cbase;
        float v00 = w3S[ly0][lx0], v01 = w3S[ly0][lx1];
        float v10 = w3S[ly1][lx0], v11 = w3S[ly1][lx1];
        float v = (1.0f - ty) * ((1.0f - tx) * v00 + tx * v01)
                +         ty  * ((1.0f - tx) * v10 + tx * v11);
        maskS[ddh][ddw] = 1.0f - v;
    }
    __syncthreads();

    // ---- streaming phase ----
    const f4 m = *(const f4*)&maskS[dh][dw4];
    // prefetched planes first (vmcnt long satisfied)
    __builtin_nontemporal_store(pf0  * m, &out[(long)(grp +  0) * PF4 + off]);
    __builtin_nontemporal_store(pf1  * m, &out[(long)(grp +  2) * PF4 + off]);
    __builtin_nontemporal_store(pf2  * m, &out[(long)(grp +  4) * PF4 + off]);
    __builtin_nontemporal_store(pf3  * m, &out[(long)(grp +  6) * PF4 + off]);
    __builtin_nontemporal_store(pf4  * m, &out[(long)(grp +  8) * PF4 + off]);
    __builtin_nontemporal_store(pf5  * m, &out[(long)(grp + 10) * PF4 + off]);
    __builtin_nontemporal_store(pf6  * m, &out[(long)(grp + 12) * PF4 + off]);
    __builtin_nontemporal_store(pf7  * m, &out[(long)(grp + 14) * PF4 + off]);
    __builtin_nontemporal_store(pf8  * m, &out[(long)(grp + 16) * PF4 + off]);
    __builtin_nontemporal_store(pf9  * m, &out[(long)(grp + 18) * PF4 + off]);
    __builtin_nontemporal_store(pf10 * m, &out[(long)(grp + 20) * PF4 + off]);
    __builtin_nontemporal_store(pf11 * m, &out[(long)(grp + 22) * PF4 + off]);
    __builtin_nontemporal_store(pf12 * m, &out[(long)(grp + 24) * PF4 + off]);
    __builtin_nontemporal_store(pf13 * m, &out[(long)(grp + 26) * PF4 + off]);
    __builtin_nontemporal_store(pf14 * m, &out[(long)(grp + 28) * PF4 + off]);
    __builtin_nontemporal_store(pf15 * m, &out[(long)(grp + 30) * PF4 + off]);
    // remaining 32 planes
    #pragma unroll 8
    for (int k = 16; k < 48; ++k) {
        long idx = (long)(grp + 2 * k) * PF4 + off;
        f4 a = face[idx];
        __builtin_nontemporal_store(a * m, &out[idx]);
    }
}

extern "C" void kernel_launch(void* const* d_in, const int* in_sizes, int n_in,
                              void* d_out, int out_size, void* d_ws, size_t ws_size,
                              hipStream_t stream) {
    const float* face = (const float*)d_in[0];   // (32,3,512,512)
    const float* lm   = (const float*)d_in[1];   // (32,68,2)
    const float* wt   = (const float*)d_in[2];   // (1,1,31,31) gaussian, normalized

    // single fused kernel: 16x32 grid of 32x16 tiles = 512 blocks (2/CU)
    k_fused<<<dim3(WW / OW, HH / OH), 256, 0, stream>>>(
        lm, wt, (const f4*)face, (f4*)d_out);
}